// Round 13
// baseline (566.679 us; speedup 1.0000x reference)
//
#include <hip/hip_runtime.h>
#include <hip/hip_bf16.h>

// VectorQuantize: B=4, N=2048, DIM=256, HEADS=4, CODEBOOK=8192, HD=64
// Established (R0-R12): inputs fp32, output fp32 (quantize ++ indices-as-floats).
// fp16 2-level split (R10-R12, absmax 0): x ~ x0 + x1/4096, 3 MFMA terms,
// score = (aA = x0e0 - 0.5||e||^2) + (aB = x0e1 + x1e0)/4096.
// Plateau autopsy (R12): pipes sum to ~58us serialized but dur=151us ->
// latency-bound, not throughput-bound. Register ledger: (,2)->128-cap+spill;
// unconstrained->256+1 block/CU. In-loop staging VALU sits on critical path.
// R13: prep pre-splits codebook into 2 f16 planes (+ exact y2); dist stages
// via global_load_lds DMA with pre-XOR-swizzled sources (LDS image identical
// to the verified conflict-free layout; read path unchanged); staging VALU and
// prefetch regs eliminated -> live ~145; __launch_bounds__(256,3) -> ~168
// budget, no spill, 3 waves/SIMD; NPART=8 grid 1024 = 3 blocks/CU.

#define HEADS    4
#define CODEBOOK 8192
#define HD       64
#define BQ       8192                  // queries per head = B*N
#define QOFF     (4 * 2048 * 256)      // quantize FLOAT elements in d_out
#define NPART    8
#define CPART    (CODEBOOK / NPART)    // 1024 codes per partition
#define SCODES   64                    // codes per stage
#define NSTAGE   (CPART / SCODES)      // 16 stages
#define RSCALE   4096.0f               // residual scale (2^12)
#define RINV     (1.0f / 4096.0f)

typedef _Float16 f16x8 __attribute__((ext_vector_type(8)));
typedef float    f32x4 __attribute__((ext_vector_type(4)));

__device__ _Float16 g_e0[HEADS * CODEBOOK * HD];  // split level 0 (4 MB)
__device__ _Float16 g_e1[HEADS * CODEBOOK * HD];  // split level 1 (x4096)
__device__ float    g_y2n[HEADS * CODEBOOK];      // -0.5*||e||^2 (exact fp32)
__device__ float    g_pval[NPART][HEADS * BQ];    // per-partition best (max score)
__device__ int      g_pidx[NPART][HEADS * BQ];    // per-partition best index

// split fp32 -> 2 fp16 levels: f ~= (float)h0 + (float)h1 / 4096, |err|<=2^-24|f|
__device__ inline void split2(float f, _Float16& h0, _Float16& h1) {
    h0 = (_Float16)f;
    float r = f - (float)h0;
    h1 = (_Float16)(r * RSCALE);
}

// ---------------- kernel 0: pre-split codebook + y2 ------------------------
// 262144 threads, one 8-float granule each; width-8 shuffle reduce for y2.
__global__ __launch_bounds__(256) void prep_kernel(const float* __restrict__ embed) {
    int gid = blockIdx.x * 256 + threadIdx.x;     // granule id
    const float* p = embed + (size_t)gid * 8;
    float4 u = *reinterpret_cast<const float4*>(p);
    float4 w = *reinterpret_cast<const float4*>(p + 4);
    float f[8] = {u.x, u.y, u.z, u.w, w.x, w.y, w.z, w.w};
    f16x8 v0, v1;
    float ss = 0.f;
#pragma unroll
    for (int j = 0; j < 8; j++) {
        _Float16 h0, h1;
        split2(f[j], h0, h1);
        v0[j] = h0; v1[j] = h1;
        ss = fmaf(f[j], f[j], ss);
    }
    *reinterpret_cast<f16x8*>(g_e0 + (size_t)gid * 8) = v0;
    *reinterpret_cast<f16x8*>(g_e1 + (size_t)gid * 8) = v1;
#pragma unroll
    for (int off = 4; off >= 1; off >>= 1) ss += __shfl_xor(ss, off, 8);
    if ((threadIdx.x & 7) == 0) g_y2n[gid >> 3] = -0.5f * ss;
}

// ---------------- kernel 1: split-fp16 MFMA scores + argmax ----------------
// grid = 1024 = head(4) x qgroup(32) x part(8); block = 256 (4 waves).
// Each wave owns 64 queries (4 pinned A row-tiles); block scans one 1024-code
// partition in 16 stages of 64 codes, staged by global_load_lds DMA into
// double-buffered LDS. DMA sources are pre-XOR-swizzled so the LDS image has
// the invariant slot(row, g^(row&7)) = granule g -> the R5-verified
// conflict-free b128 read path is unchanged.
// MFMA 16x16x32_f16 layouts (HW-verified family):
//   A: lane -> A[m=lane&15][k=quad*8+j];  B: lane -> B[k=quad*8+j][n=lane&15]
//   C: lane -> col=lane&15, row=quad*4+reg
__global__ __launch_bounds__(256, 3) void dist_kernel(const float* __restrict__ x) {
    __shared__ __align__(16) _Float16 tile[2][2][SCODES * 64];   // 32768 B
    __shared__ float y2s[CPART];                                 // 4096 B

    const int bid  = blockIdx.x;
    const int part = bid & 7;
    const int qg   = (bid >> 3) & 31;
    const int h    = bid >> 8;
    const int t    = threadIdx.x;
    const int wave = t >> 6;
    const int lane = t & 63;
    const int col  = lane & 15;
    const int quad = lane >> 4;

    const int qbase = qg * 256 + wave * 64;       // this wave's 64 queries
    const int cbase = part * CPART;

    // A fragments a[rowtile][level][khalf], split once from fp32 x
    f16x8 a[4][2][2];
#pragma unroll
    for (int rt = 0; rt < 4; rt++) {
#pragma unroll
        for (int kh = 0; kh < 2; kh++) {
            const float* p = x + ((size_t)(qbase + rt * 16 + col) * 256 + h * 64 + kh * 32 + quad * 8);
#pragma unroll
            for (int j = 0; j < 8; j++) {
                _Float16 h0, h1;
                split2(p[j], h0, h1);
                a[rt][0][kh][j] = h0;
                a[rt][1][kh][j] = h1;
            }
        }
    }

    // DMA staging geometry: dst slot for thread t in round i is linear
    // (base + i*4KB + wave*1KB + lane*16B); the source granule is XOR'd so the
    // LDS image is swizzled: row r = (i&1)*32 + (t>>3), src granule
    // (t&7)^((t>>3)&7). rowoff is stage-independent.
    const size_t pb     = ((size_t)h * CODEBOOK + cbase) * HD;
    const int    rowoff = (t >> 3) * 64 + (((t & 7) ^ ((t >> 3) & 7)) << 3);  // f16 units
    const _Float16* sA  = g_e0 + pb + rowoff;
    const _Float16* sB  = g_e1 + pb + rowoff;

    auto dma_stage = [&](int buf, int stg) {
        const _Float16* a0 = sA + (size_t)stg * (SCODES * HD);
        const _Float16* b0 = sB + (size_t)stg * (SCODES * HD);
        _Float16* d = &tile[buf][0][0] + wave * 512;   // wave-uniform base
        __builtin_amdgcn_global_load_lds((const __attribute__((address_space(1))) void*)a0,
                                         (__attribute__((address_space(3))) void*)d, 16, 0, 0);
        __builtin_amdgcn_global_load_lds((const __attribute__((address_space(1))) void*)(a0 + 2048),
                                         (__attribute__((address_space(3))) void*)(d + 2048), 16, 0, 0);
        __builtin_amdgcn_global_load_lds((const __attribute__((address_space(1))) void*)b0,
                                         (__attribute__((address_space(3))) void*)(d + 4096), 16, 0, 0);
        __builtin_amdgcn_global_load_lds((const __attribute__((address_space(1))) void*)(b0 + 2048),
                                         (__attribute__((address_space(3))) void*)(d + 6144), 16, 0, 0);
    };

    float bv[4][4]; int bc[4][4];
#pragma unroll
    for (int rt = 0; rt < 4; rt++)
#pragma unroll
        for (int r = 0; r < 4; r++) { bv[rt][r] = -3.4e38f; bc[rt][r] = 0; }

    // preamble: DMA stage 0, y2 partition -> LDS (4 floats/thread), publish
    dma_stage(0, 0);
    *reinterpret_cast<float4*>(y2s + t * 4) =
        *reinterpret_cast<const float4*>(g_y2n + h * CODEBOOK + cbase + t * 4);
    __syncthreads();   // drains vmcnt -> DMA + y2 visible

    const int swbase = col & 7;                    // read-side swizzle key

    for (int s = 0; s < NSTAGE; s++) {
        // DMA stage s+1 into the other buffer; it drains at THIS stage's end
        // barrier (a full stage of MFMA covers the latency). Writing buf^1 is
        // safe: its readers (stage s-1) passed the previous barrier.
        if (s + 1 < NSTAGE) dma_stage((s + 1) & 1, s + 1);

#pragma unroll
        for (int inner = 0; inner < 4; inner++) {
            const int rbase = (inner * 16 + col) * 64;     // row offset in plane
            f16x8 b[2][2];
#pragma unroll
            for (int lvl = 0; lvl < 2; lvl++)
#pragma unroll
                for (int kh = 0; kh < 2; kh++)
                    b[lvl][kh] = *reinterpret_cast<const f16x8*>(
                        &tile[s & 1][lvl][rbase + ((((kh << 2) | quad) ^ swbase) << 3)]);

            const int   c   = s * SCODES + inner * 16 + col;   // partition-local code
            const float ycn = y2s[c];                          // -0.5*||e_c||^2
#pragma unroll
            for (int rt = 0; rt < 4; rt++) {
                f32x4 aA = {ycn, ycn, ycn, ycn};               // init-fold of -0.5||e||^2
                f32x4 aB = {0.f, 0.f, 0.f, 0.f};
#pragma unroll
                for (int kh = 0; kh < 2; kh++) {               // 3 terms x 2 kh
                    aA = __builtin_amdgcn_mfma_f32_16x16x32_f16(a[rt][0][kh], b[0][kh], aA, 0, 0, 0);
                    aB = __builtin_amdgcn_mfma_f32_16x16x32_f16(a[rt][0][kh], b[1][kh], aB, 0, 0, 0);
                    aB = __builtin_amdgcn_mfma_f32_16x16x32_f16(a[rt][1][kh], b[0][kh], aB, 0, 0, 0);
                }
#pragma unroll
                for (int r = 0; r < 4; r++) {
                    float sv = fmaf(aB[r], RINV, aA[r]);       // xy - 0.5||e||^2
                    if (sv > bv[rt][r]) { bv[rt][r] = sv; bc[rt][r] = c; }
                }
            }
        }
        __syncthreads();
    }

    // reduce across 16 column slots; lexicographic (max val, min idx) =
    // np first-argmax tie-break
#pragma unroll
    for (int rt = 0; rt < 4; rt++) {
#pragma unroll
        for (int r = 0; r < 4; r++) {
            float v = bv[rt][r]; int c = bc[rt][r];
#pragma unroll
            for (int off = 8; off >= 1; off >>= 1) {
                float ov = __shfl_xor(v, off, 16); int oc = __shfl_xor(c, off, 16);
                if (ov > v || (ov == v && oc < c)) { v = ov; c = oc; }
            }
            if (col == 0) {
                int q = h * BQ + qbase + rt * 16 + quad * 4 + r;
                g_pval[part][q] = v; g_pidx[part][q] = cbase + c;
            }
        }
    }
}

// ---------------- kernel 2: merge partitions + gather + index write --------
__global__ __launch_bounds__(256) void merge_kernel(const float* __restrict__ embed,
                                                    float* __restrict__ out) {
    int id = blockIdx.x * 256 + threadIdx.x;   // m*4 + h  (m-major, coalesced idx write)
    int m = id >> 2;
    int h = id & 3;
    int q = h * BQ + m;

    float bv = g_pval[0][q]; int bc = g_pidx[0][q];
#pragma unroll
    for (int p = 1; p < NPART; p++) {
        float v = g_pval[p][q]; int c = g_pidx[p][q];
        if (v > bv || (v == bv && c < bc)) { bv = v; bc = c; }
    }

    out[QOFF + id] = (float)bc;                // embed_ind[b][n][h] as fp32 value

    int idx = bc & (CODEBOOK - 1);             // defensive in-range
    const float* src = embed + ((size_t)h * CODEBOOK + idx) * HD;
    float*       dst = out + (size_t)m * 256 + h * 64;
#pragma unroll
    for (int i = 0; i < 16; i++)               // 64 fp32, verbatim
        *reinterpret_cast<float4*>(dst + i * 4) = *reinterpret_cast<const float4*>(src + i * 4);
}

extern "C" void kernel_launch(void* const* d_in, const int* in_sizes, int n_in,
                              void* d_out, int out_size, void* d_ws, size_t ws_size,
                              hipStream_t stream) {
    const float* x     = (const float*)d_in[0];
    const float* embed = (const float*)d_in[1];
    float*       out   = (float*)d_out;

    prep_kernel <<<1024, 256, 0, stream>>>(embed);
    dist_kernel <<<1024, 256, 0, stream>>>(x);
    merge_kernel<<<128,  256, 0, stream>>>(embed, out);
}

// Round 14
// 201.626 us; speedup vs baseline: 2.8105x; 2.8105x over previous
//
#include <hip/hip_runtime.h>
#include <hip/hip_bf16.h>

// VectorQuantize: B=4, N=2048, DIM=256, HEADS=4, CODEBOOK=8192, HD=64
// Established (R0-R13): inputs fp32, output fp32 (quantize ++ indices-as-floats).
// fp16 2-level split (absmax 0 since R10): x ~ x0 + x1/4096, 3 MFMA terms,
// score = (aA = x0e0 - 0.5||e||^2) + (aB = x0e1 + x1e0)/4096.
// Register ledger (R6/R10/R11/R13): any __launch_bounds__ min-waves splits the
// unified file ~50/50 arch/accum ((,2)->128, (,3)->84, (,4)->64 arch) and
// spills if live-arch exceeds it; unbounded -> 256 regs, 1 block/CU.
// Plateau autopsy (R5-R13): serialized pipe sum ~58us, measured 138-151us ->
// the 2-barrier-per-stage LDS K-loop exposes latency collectively. R14 kills
// the K-loop barrier: B streams DIRECTLY from global (pre-split f16 planes,
// 2 MB/head, L2-resident per XCD via bid swizzle head=(bid&7)>>1); no LDS, no
// __syncthreads in the loop; live-arch ~120 fits (,2)'s 128 cleanly.

#define HEADS    4
#define CODEBOOK 8192
#define HD       64
#define BQ       8192                  // queries per head = B*N
#define QOFF     (4 * 2048 * 256)      // quantize FLOAT elements in d_out
#define NPART    4
#define CPART    (CODEBOOK / NPART)    // 2048 codes per partition
#define RSCALE   4096.0f               // residual scale (2^12)
#define RINV     (1.0f / 4096.0f)

typedef _Float16 f16x8 __attribute__((ext_vector_type(8)));
typedef float    f32x4 __attribute__((ext_vector_type(4)));

__device__ _Float16 g_e0[HEADS * CODEBOOK * HD];  // split level 0 (4 MB)
__device__ _Float16 g_e1[HEADS * CODEBOOK * HD];  // split level 1 (x4096)
__device__ float    g_y2n[HEADS * CODEBOOK];      // -0.5*||e||^2 (exact fp32)
__device__ float    g_pval[NPART][HEADS * BQ];    // per-partition best (max score)
__device__ int      g_pidx[NPART][HEADS * BQ];    // per-partition best index

// split fp32 -> 2 fp16 levels: f ~= (float)h0 + (float)h1 / 4096, |err|<=2^-24|f|
__device__ inline void split2(float f, _Float16& h0, _Float16& h1) {
    h0 = (_Float16)f;
    float r = f - (float)h0;
    h1 = (_Float16)(r * RSCALE);
}

// ---------------- kernel 0: pre-split codebook + y2 ------------------------
__global__ __launch_bounds__(256) void prep_kernel(const float* __restrict__ embed) {
    int gid = blockIdx.x * 256 + threadIdx.x;     // 8-float granule id
    const float* p = embed + (size_t)gid * 8;
    float4 u = *reinterpret_cast<const float4*>(p);
    float4 w = *reinterpret_cast<const float4*>(p + 4);
    float f[8] = {u.x, u.y, u.z, u.w, w.x, w.y, w.z, w.w};
    f16x8 v0, v1;
    float ss = 0.f;
#pragma unroll
    for (int j = 0; j < 8; j++) {
        _Float16 h0, h1;
        split2(f[j], h0, h1);
        v0[j] = h0; v1[j] = h1;
        ss = fmaf(f[j], f[j], ss);
    }
    *reinterpret_cast<f16x8*>(g_e0 + (size_t)gid * 8) = v0;
    *reinterpret_cast<f16x8*>(g_e1 + (size_t)gid * 8) = v1;
#pragma unroll
    for (int off = 4; off >= 1; off >>= 1) ss += __shfl_xor(ss, off, 8);
    if ((threadIdx.x & 7) == 0) g_y2n[gid >> 3] = -0.5f * ss;
}

// ---------------- kernel 1: barrier-free split-fp16 MFMA + argmax ----------
// grid = 512; bid -> xcd = bid&7, head = xcd>>1 (each XCD sees ONE head's
// 2 MB planes -> L2-resident), idx = (bid>>3)*2 + (bid&1) in 0..127,
// part = idx&3, qg = idx>>2. Block = 256 (4 waves); each wave owns 64 queries
// (4 pinned A row-tiles) and streams its 2048-code partition straight from
// global in 16-code steps: 4 b128 plane loads + 1 y2 load + 24 MFMA. No LDS,
// no in-loop __syncthreads -- waves are fully decoupled; the compiler issues
// fine-grained vmcnt waits (loads in flight across MFMA).
// MFMA 16x16x32_f16 layouts (HW-verified):
//   A: lane -> A[m=lane&15][k=quad*8+j];  B: lane -> B[k=quad*8+j][n=lane&15]
//   C: lane -> col=lane&15, row=quad*4+reg
__global__ __launch_bounds__(256, 2) void dist_kernel(const float* __restrict__ x) {
    const int bid  = blockIdx.x;
    const int head = (bid & 7) >> 1;
    const int idx  = ((bid >> 3) << 1) | (bid & 1);
    const int part = idx & 3;
    const int qg   = idx >> 2;                    // 0..31
    const int t    = threadIdx.x;
    const int wave = t >> 6;
    const int lane = t & 63;
    const int col  = lane & 15;
    const int quad = lane >> 4;

    const int qbase = qg * 256 + wave * 64;       // this wave's 64 queries
    const int cbase = part * CPART;

    // A fragments a[rowtile][level][khalf], split once from fp32 x
    f16x8 a[4][2][2];
#pragma unroll
    for (int rt = 0; rt < 4; rt++) {
#pragma unroll
        for (int kh = 0; kh < 2; kh++) {
            const float* p = x + ((size_t)(qbase + rt * 16 + col) * 256 + head * 64 + kh * 32 + quad * 8);
#pragma unroll
            for (int j = 0; j < 8; j++) {
                _Float16 h0, h1;
                split2(p[j], h0, h1);
                a[rt][0][kh][j] = h0;
                a[rt][1][kh][j] = h1;
            }
        }
    }

    // B stream bases: lane reads row (cc+col), 16B granule quad of each 64B half
    const size_t pb  = ((size_t)head * CODEBOOK + cbase) * HD;
    const _Float16* p0 = g_e0 + pb + (size_t)col * HD + quad * 8;
    const _Float16* p1 = g_e1 + pb + (size_t)col * HD + quad * 8;
    const float*    py = g_y2n + head * CODEBOOK + cbase + col;

    float bv[4][4]; int bc[4][4];
#pragma unroll
    for (int rt = 0; rt < 4; rt++)
#pragma unroll
        for (int r = 0; r < 4; r++) { bv[rt][r] = -3.4e38f; bc[rt][r] = 0; }

#pragma unroll 2
    for (int cc = 0; cc < CPART; cc += 16) {
        const size_t o = (size_t)cc * HD;
        f16x8 b00 = *reinterpret_cast<const f16x8*>(p0 + o);        // lvl0, k 0..31
        f16x8 b01 = *reinterpret_cast<const f16x8*>(p0 + o + 32);   // lvl0, k 32..63
        f16x8 b10 = *reinterpret_cast<const f16x8*>(p1 + o);        // lvl1, k 0..31
        f16x8 b11 = *reinterpret_cast<const f16x8*>(p1 + o + 32);   // lvl1, k 32..63
        const float ycn = py[cc];                                   // -0.5*||e_c||^2
        const int   c   = cc + col;

#pragma unroll
        for (int rt = 0; rt < 4; rt++) {
            f32x4 aA = {ycn, ycn, ycn, ycn};       // init-fold of -0.5||e||^2
            f32x4 aB = {0.f, 0.f, 0.f, 0.f};
            aA = __builtin_amdgcn_mfma_f32_16x16x32_f16(a[rt][0][0], b00, aA, 0, 0, 0);
            aB = __builtin_amdgcn_mfma_f32_16x16x32_f16(a[rt][0][0], b10, aB, 0, 0, 0);
            aA = __builtin_amdgcn_mfma_f32_16x16x32_f16(a[rt][0][1], b01, aA, 0, 0, 0);
            aB = __builtin_amdgcn_mfma_f32_16x16x32_f16(a[rt][1][0], b00, aB, 0, 0, 0);
            aB = __builtin_amdgcn_mfma_f32_16x16x32_f16(a[rt][0][1], b11, aB, 0, 0, 0);
            aB = __builtin_amdgcn_mfma_f32_16x16x32_f16(a[rt][1][1], b01, aB, 0, 0, 0);
#pragma unroll
            for (int r = 0; r < 4; r++) {
                float sv = fmaf(aB[r], RINV, aA[r]);   // xy - 0.5||e||^2
                if (sv > bv[rt][r]) { bv[rt][r] = sv; bc[rt][r] = c; }
            }
        }
    }

    // reduce across 16 column slots; lexicographic (max val, min idx) =
    // np first-argmax tie-break
#pragma unroll
    for (int rt = 0; rt < 4; rt++) {
#pragma unroll
        for (int r = 0; r < 4; r++) {
            float v = bv[rt][r]; int c = bc[rt][r];
#pragma unroll
            for (int off = 8; off >= 1; off >>= 1) {
                float ov = __shfl_xor(v, off, 16); int oc = __shfl_xor(c, off, 16);
                if (ov > v || (ov == v && oc < c)) { v = ov; c = oc; }
            }
            if (col == 0) {
                int q = head * BQ + qbase + rt * 16 + quad * 4 + r;
                g_pval[part][q] = v; g_pidx[part][q] = cbase + c;
            }
        }
    }
}

// ---------------- kernel 2: merge partitions + gather + index write --------
__global__ __launch_bounds__(256) void merge_kernel(const float* __restrict__ embed,
                                                    float* __restrict__ out) {
    int id = blockIdx.x * 256 + threadIdx.x;   // m*4 + h  (m-major, coalesced idx write)
    int m = id >> 2;
    int h = id & 3;
    int q = h * BQ + m;

    float bv = g_pval[0][q]; int bc = g_pidx[0][q];
#pragma unroll
    for (int p = 1; p < NPART; p++) {
        float v = g_pval[p][q]; int c = g_pidx[p][q];
        if (v > bv || (v == bv && c < bc)) { bv = v; bc = c; }
    }

    out[QOFF + id] = (float)bc;                // embed_ind[b][n][h] as fp32 value

    int idx = bc & (CODEBOOK - 1);             // defensive in-range
    const float* src = embed + ((size_t)h * CODEBOOK + idx) * HD;
    float*       dst = out + (size_t)m * 256 + h * 64;
#pragma unroll
    for (int i = 0; i < 16; i++)               // 64 fp32, verbatim
        *reinterpret_cast<float4*>(dst + i * 4) = *reinterpret_cast<const float4*>(src + i * 4);
}

extern "C" void kernel_launch(void* const* d_in, const int* in_sizes, int n_in,
                              void* d_out, int out_size, void* d_ws, size_t ws_size,
                              hipStream_t stream) {
    const float* x     = (const float*)d_in[0];
    const float* embed = (const float*)d_in[1];
    float*       out   = (float*)d_out;

    prep_kernel <<<1024, 256, 0, stream>>>(embed);
    dist_kernel <<<512,  256, 0, stream>>>(x);
    merge_kernel<<<128,  256, 0, stream>>>(embed, out);
}